// Round 9
// baseline (464.255 us; speedup 1.0000x reference)
//
#include <hip/hip_runtime.h>
#include <hip/hip_bf16.h>

#define N_NODES 50000
#define N_EDGES 600000
#define N_GRAPHS 64
#define HID 128
#define NLAYERS 4
#define IN_DIM 5
#define NCLS 5
#define EPS 1e-5f
#define POOL_CHUNKS 16
#define BSLOT 64  // BN-stat atomic slots (per layer)
#define WS 136    // bf16 LDS row stride (MFMA kernel)

// bucket-sort CSR build: bucket = dst>>6 (64 nodes/bucket)
#define NBUCK ((N_NODES + 63) / 64)       // 782
#define BCAP 1024                          // >= mean 768 + 9 sigma (fixed input)
#define EDGE_BLK ((N_EDGES + 255) / 256)   // 2344
#define WT_BLK ((NLAYERS * HID * HID) / 256)  // 256

typedef __attribute__((ext_vector_type(8))) short s16x8;
typedef __attribute__((ext_vector_type(4))) float f32x4;

// bf16 helpers (RNE)
__device__ __forceinline__ unsigned short f2bf(float x) {
    unsigned u = __float_as_uint(x);
    unsigned r = (u + 0x7fffu + ((u >> 16) & 1u)) >> 16;
    return (unsigned short)r;
}
__device__ __forceinline__ float2 bfpair(unsigned u) {
    float2 r;
    r.x = __uint_as_float(u << 16);
    r.y = __uint_as_float(u & 0xffff0000u);
    return r;
}
__device__ __forceinline__ float bf2f(unsigned short s) {
    return __uint_as_float(((unsigned)s) << 16);
}

// ---------------- build pass 1: bucket append (+ gstart + W transpose) ----------------
// Edge e -> bucket dst>>6, packed u32 = (src<<6)|(dst&63)  [src<65536, fits 22b].
// Appends go to 782 dense per-bucket streams: one hot line per bucket instead
// of 37.5K ping-ponging lines (R8 lesson: scatter amp is line-granular).
// bcur[b] ends as the bucket size. Trailing blocks: gstart search + WtG.

__global__ void k_bucket(const int* __restrict__ src, const int* __restrict__ dst,
                         const int* __restrict__ batch, const float* __restrict__ Wg,
                         int* __restrict__ bcur, unsigned* __restrict__ ebuf,
                         int* __restrict__ gstart, unsigned short* __restrict__ WtG) {
    int b = blockIdx.x, t = threadIdx.x;
    if (b < EDGE_BLK) {
        int e = b * 256 + t;
        if (e < N_EDGES) {
            int d = dst[e];
            int s = src[e];
            int bk = d >> 6;
            int pos = atomicAdd(&bcur[bk], 1);
            ebuf[bk * BCAP + pos] = ((unsigned)s << 6) | (unsigned)(d & 63);
        }
    } else if (b == EDGE_BLK) {
        if (t <= N_GRAPHS) {
            int lo = 0, hi = N_NODES;
            while (lo < hi) {
                int mid = (lo + hi) >> 1;
                if (batch[mid] < t) lo = mid + 1; else hi = mid;
            }
            gstart[t] = lo;
        }
    } else {
        int idx = (b - EDGE_BLK - 1) * 256 + t;  // < NLAYERS*HID*HID
        int l = idx >> 14;
        int r = idx & 16383;
        int n = r >> 7, k = r & 127;
        WtG[idx] = f2bf(Wg[l * HID * HID + k * HID + n]);
    }
}

// ---------------- build pass 2: scan bucket sizes -> bases; rp[N] ----------------

__global__ __launch_bounds__(1024) void k_bscan(const int* __restrict__ bcur,
                                                int* __restrict__ bbase,
                                                int* __restrict__ rp) {
    __shared__ int s[1024];
    int t = threadIdx.x;
    int v = (t < NBUCK) ? bcur[t] : 0;
    s[t] = v;
    __syncthreads();
    for (int off = 1; off < 1024; off <<= 1) {
        int x = (t >= off) ? s[t - off] : 0;
        __syncthreads();
        s[t] += x;
        __syncthreads();
    }
    if (t < NBUCK) bbase[t] = s[t] - v;  // exclusive base
    if (t == NBUCK - 1) {
        bbase[NBUCK] = s[t];
        rp[N_NODES] = s[t];  // = N_EDGES
    }
}

// ---------------- build pass 3: per-bucket LDS counting sort ----------------
// Block b: load bucket edges to LDS, histogram 64 node bins, scan, write
// rp/dinv for its nodes, scatter cols to block-private dense cwc slots.

__global__ __launch_bounds__(256) void k_bsort(const unsigned* __restrict__ ebuf,
                                               const int* __restrict__ bcur,
                                               const int* __restrict__ bbase,
                                               int* __restrict__ rp,
                                               float* __restrict__ dinv,
                                               int* __restrict__ cwc) {
    __shared__ unsigned le[BCAP];
    __shared__ int cnt[64];
    __shared__ int sc[64];
    __shared__ int cur[64];
    int b = blockIdx.x, t = threadIdx.x;
    int sz = bcur[b];
    int base = bbase[b];
    int n0 = b * 64;
    for (int i = t; i < sz; i += 256) le[i] = ebuf[b * BCAP + i];
    if (t < 64) cnt[t] = 0;
    __syncthreads();
    for (int i = t; i < sz; i += 256) atomicAdd(&cnt[le[i] & 63u], 1);
    __syncthreads();
    // exclusive scan over the 64 bins
    int vc = (t < 64) ? cnt[t] : 0;
    if (t < 64) sc[t] = vc;
    __syncthreads();
    for (int off = 1; off < 64; off <<= 1) {
        int x = (t < 64 && t >= off) ? sc[t - off] : 0;
        __syncthreads();
        if (t < 64) sc[t] += x;
        __syncthreads();
    }
    if (t < 64) {
        int excl = sc[t] - vc;
        cur[t] = excl;
        int node = n0 + t;
        if (node < N_NODES) {
            rp[node] = base + excl;
            dinv[node] = rsqrtf((float)(vc + 1));
        }
    }
    __syncthreads();
    for (int i = t; i < sz; i += 256) {
        unsigned u = le[i];
        int p = atomicAdd(&cur[u & 63u], 1);
        cwc[base + p] = (int)(u >> 6);
    }
}

// ---------------- GEMM (MFMA): Bm(bf16) = act(in) @ W (R2-proven) ----------------

__global__ __launch_bounds__(256, 3) void k_gemmM(const unsigned short* __restrict__ Abf,
                                                  const float* __restrict__ x,
                                                  const float* __restrict__ Wp,
                                                  const float* __restrict__ bp,
                                                  const unsigned short* __restrict__ WtG,
                                                  unsigned short* __restrict__ Bm,
                                                  const float* __restrict__ psum,
                                                  const float* __restrict__ psq,
                                                  const float* __restrict__ gamma,
                                                  const float* __restrict__ beta,
                                                  int layer0) {
    __shared__ unsigned short Wt[HID * WS];
    __shared__ unsigned short Al[64 * WS];
    __shared__ float scl[HID], shf[HID];
    int t = threadIdx.x;
    {
        const uint4* Wg4 = (const uint4*)WtG;
        for (int idx = t; idx < HID * 16; idx += 256) {
            int n = idx >> 4, c = idx & 15;
            *(uint4*)&Wt[n * WS + c * 8] = Wg4[idx];
        }
    }
    if (!layer0 && t < HID) {
        float s = 0.f, s2 = 0.f;
#pragma unroll 8
        for (int b = 0; b < BSLOT; b++) {
            s += psum[b * HID + t];
            s2 += psq[b * HID + t];
        }
        const float invN = 1.f / (float)N_NODES;
        float mu = s * invN;
        float var = s2 * invN - mu * mu;
        float rs = rsqrtf(var + EPS) * gamma[t];
        scl[t] = rs;
        shf[t] = beta[t] - mu * rs;
    }
    int lane = t & 63, wv = t >> 6;
    int rbase = (wv & 1) * 32;
    int cbase = (wv >> 1) * 64;
    int mr = lane & 15, q = lane >> 4;
    const int numTiles = (N_NODES + 63) / 64;
    for (int tile = blockIdx.x; tile < numTiles; tile += gridDim.x) {
        int n0 = tile * 64;
        int limRow = min(64, N_NODES - n0);
        __syncthreads();  // orders scl/Wt writes (1st iter) + Al reuse safety
        if (layer0) {
            for (int idx = t; idx < 64 * HID; idx += 256) {
                int n = idx >> 7, k = idx & 127;
                int node = n0 + n;
                float acc = 0.f;
                if (node < N_NODES) {
                    acc = bp[k];
#pragma unroll
                    for (int j = 0; j < IN_DIM; j++) acc += x[node * IN_DIM + j] * Wp[j * HID + k];
                }
                Al[n * WS + k] = f2bf(acc);
            }
        } else {
            const uint2* Ag = (const uint2*)(Abf + (size_t)n0 * HID);
            for (int idx = t; idx < 64 * 32; idx += 256) {
                int row = idx >> 5, c4 = idx & 31;
                uint2 u = (row < limRow) ? Ag[row * 32 + c4] : make_uint2(0u, 0u);
                float2 ab = bfpair(u.x);
                float2 cd = bfpair(u.y);
                int kf = c4 * 4;
                float4 sc = *(const float4*)&scl[kf];
                float4 sh = *(const float4*)&shf[kf];
                float v0 = fmaxf(ab.x * sc.x + sh.x, 0.f);
                float v1 = fmaxf(ab.y * sc.y + sh.y, 0.f);
                float v2 = fmaxf(cd.x * sc.z + sh.z, 0.f);
                float v3 = fmaxf(cd.y * sc.w + sh.w, 0.f);
                unsigned lo = (unsigned)f2bf(v0) | ((unsigned)f2bf(v1) << 16);
                unsigned hi = (unsigned)f2bf(v2) | ((unsigned)f2bf(v3) << 16);
                *(uint2*)&Al[row * WS + kf] = make_uint2(lo, hi);
            }
        }
        __syncthreads();
        f32x4 acc[2][4];
#pragma unroll
        for (int rt = 0; rt < 2; rt++)
#pragma unroll
            for (int ct = 0; ct < 4; ct++) acc[rt][ct] = (f32x4){0.f, 0.f, 0.f, 0.f};
#pragma unroll
        for (int kk = 0; kk < HID; kk += 32) {
            s16x8 a0 = *(const s16x8*)&Al[(rbase + mr) * WS + kk + q * 8];
            s16x8 a1 = *(const s16x8*)&Al[(rbase + 16 + mr) * WS + kk + q * 8];
#pragma unroll
            for (int ct = 0; ct < 4; ct++) {
                s16x8 b = *(const s16x8*)&Wt[(cbase + ct * 16 + mr) * WS + kk + q * 8];
                acc[0][ct] = __builtin_amdgcn_mfma_f32_16x16x32_bf16(a0, b, acc[0][ct], 0, 0, 0);
                acc[1][ct] = __builtin_amdgcn_mfma_f32_16x16x32_bf16(a1, b, acc[1][ct], 0, 0, 0);
            }
        }
        __syncthreads();  // all waves done reading Al fragments
        // stage C tile into Al (bf16), then coalesced uint4 global stores
#pragma unroll
        for (int rt = 0; rt < 2; rt++)
#pragma unroll
            for (int ct = 0; ct < 4; ct++)
#pragma unroll
                for (int r = 0; r < 4; r++) {
                    int rloc = rbase + rt * 16 + q * 4 + r;
                    int f = cbase + ct * 16 + mr;
                    Al[rloc * WS + f] = f2bf(acc[rt][ct][r]);
                }
        __syncthreads();
        for (int idx = t; idx < 64 * 16; idx += 256) {
            int row = idx >> 4, c = idx & 15;
            if (row < limRow)
                *(uint4*)&Bm[(size_t)(n0 + row) * HID + c * 8] = *(const uint4*)&Al[row * WS + c * 8];
        }
    }
}

// ---------------- CSR gather + fused BN partial stats (R8-proven) ----------------

__global__ __launch_bounds__(256) void k_gather(const uint4* __restrict__ Bm4,
                                                const int* __restrict__ rp,
                                                const int* __restrict__ cwc,
                                                const float* __restrict__ dinv,
                                                const float* __restrict__ bg,
                                                unsigned short* __restrict__ Aout,
                                                float* __restrict__ psum,
                                                float* __restrict__ psq) {
    __shared__ float ls[4 * HID], lq[4 * HID];
    int wave = threadIdx.x >> 6;
    int lane = threadIdx.x & 63;
    int s = lane & 15;   // 16B feature chunk: features s*8 .. s*8+7
    int p = lane >> 4;   // node slot 0..3 within wave
    int f = s * 8;
    int v = blockIdx.x * 16 + wave * 4 + p;
    int beg = rp[v], end = rp[v + 1];
    float dv = dinv[v];
    float a0, a1, a2, a3, a4, a5, a6, a7;
    {
        uint4 u = Bm4[(size_t)v * 16 + s];
        float2 q0 = bfpair(u.x), q1 = bfpair(u.y), q2 = bfpair(u.z), q3 = bfpair(u.w);
        a0 = q0.x * dv; a1 = q0.y * dv; a2 = q1.x * dv; a3 = q1.y * dv;
        a4 = q2.x * dv; a5 = q2.y * dv; a6 = q3.x * dv; a7 = q3.y * dv;
    }
    int e = beg;
    for (; e + 1 < end; e += 2) {
        int c0 = cwc[e];
        int c1 = cwc[e + 1];
        uint4 u0 = Bm4[(size_t)c0 * 16 + s];
        uint4 u1 = Bm4[(size_t)c1 * 16 + s];
        float w0 = dinv[c0];
        float w1 = dinv[c1];
        float2 x0 = bfpair(u0.x), x1 = bfpair(u0.y), x2 = bfpair(u0.z), x3 = bfpair(u0.w);
        float2 y0 = bfpair(u1.x), y1 = bfpair(u1.y), y2 = bfpair(u1.z), y3 = bfpair(u1.w);
        a0 += x0.x * w0 + y0.x * w1;
        a1 += x0.y * w0 + y0.y * w1;
        a2 += x1.x * w0 + y1.x * w1;
        a3 += x1.y * w0 + y1.y * w1;
        a4 += x2.x * w0 + y2.x * w1;
        a5 += x2.y * w0 + y2.y * w1;
        a6 += x3.x * w0 + y3.x * w1;
        a7 += x3.y * w0 + y3.y * w1;
    }
    if (e < end) {
        int c0 = cwc[e];
        uint4 u = Bm4[(size_t)c0 * 16 + s];
        float w = dinv[c0];
        float2 x0 = bfpair(u.x), x1 = bfpair(u.y), x2 = bfpair(u.z), x3 = bfpair(u.w);
        a0 += x0.x * w; a1 += x0.y * w; a2 += x1.x * w; a3 += x1.y * w;
        a4 += x2.x * w; a5 += x2.y * w; a6 += x3.x * w; a7 += x3.y * w;
    }
    float r0 = a0 * dv + bg[f + 0];
    float r1 = a1 * dv + bg[f + 1];
    float r2 = a2 * dv + bg[f + 2];
    float r3 = a3 * dv + bg[f + 3];
    float r4 = a4 * dv + bg[f + 4];
    float r5 = a5 * dv + bg[f + 5];
    float r6 = a6 * dv + bg[f + 6];
    float r7 = a7 * dv + bg[f + 7];
    unsigned short b0 = f2bf(r0), b1 = f2bf(r1), b2 = f2bf(r2), b3 = f2bf(r3);
    unsigned short b4 = f2bf(r4), b5 = f2bf(r5), b6 = f2bf(r6), b7 = f2bf(r7);
    uint4 o;
    o.x = (unsigned)b0 | ((unsigned)b1 << 16);
    o.y = (unsigned)b2 | ((unsigned)b3 << 16);
    o.z = (unsigned)b4 | ((unsigned)b5 << 16);
    o.w = (unsigned)b6 | ((unsigned)b7 << 16);
    *(uint4*)&Aout[(size_t)v * HID + f] = o;
    // BN stats on the bf16-rounded values (what the next GEMM sees)
    float v0 = bf2f(b0), v1 = bf2f(b1), v2 = bf2f(b2), v3 = bf2f(b3);
    float v4 = bf2f(b4), v5 = bf2f(b5), v6 = bf2f(b6), v7 = bf2f(b7);
    float ts0 = v0, ts1 = v1, ts2 = v2, ts3 = v3;
    float ts4 = v4, ts5 = v5, ts6 = v6, ts7 = v7;
    float tq0 = v0 * v0, tq1 = v1 * v1, tq2 = v2 * v2, tq3 = v3 * v3;
    float tq4 = v4 * v4, tq5 = v5 * v5, tq6 = v6 * v6, tq7 = v7 * v7;
    ts0 += __shfl_xor(ts0, 16); ts1 += __shfl_xor(ts1, 16);
    ts2 += __shfl_xor(ts2, 16); ts3 += __shfl_xor(ts3, 16);
    ts4 += __shfl_xor(ts4, 16); ts5 += __shfl_xor(ts5, 16);
    ts6 += __shfl_xor(ts6, 16); ts7 += __shfl_xor(ts7, 16);
    tq0 += __shfl_xor(tq0, 16); tq1 += __shfl_xor(tq1, 16);
    tq2 += __shfl_xor(tq2, 16); tq3 += __shfl_xor(tq3, 16);
    tq4 += __shfl_xor(tq4, 16); tq5 += __shfl_xor(tq5, 16);
    tq6 += __shfl_xor(tq6, 16); tq7 += __shfl_xor(tq7, 16);
    ts0 += __shfl_xor(ts0, 32); ts1 += __shfl_xor(ts1, 32);
    ts2 += __shfl_xor(ts2, 32); ts3 += __shfl_xor(ts3, 32);
    ts4 += __shfl_xor(ts4, 32); ts5 += __shfl_xor(ts5, 32);
    ts6 += __shfl_xor(ts6, 32); ts7 += __shfl_xor(ts7, 32);
    tq0 += __shfl_xor(tq0, 32); tq1 += __shfl_xor(tq1, 32);
    tq2 += __shfl_xor(tq2, 32); tq3 += __shfl_xor(tq3, 32);
    tq4 += __shfl_xor(tq4, 32); tq5 += __shfl_xor(tq5, 32);
    tq6 += __shfl_xor(tq6, 32); tq7 += __shfl_xor(tq7, 32);
    if (p == 0) {
        float* lsw = &ls[wave * HID + f];
        float* lqw = &lq[wave * HID + f];
        lsw[0] = ts0; lsw[1] = ts1; lsw[2] = ts2; lsw[3] = ts3;
        lsw[4] = ts4; lsw[5] = ts5; lsw[6] = ts6; lsw[7] = ts7;
        lqw[0] = tq0; lqw[1] = tq1; lqw[2] = tq2; lqw[3] = tq3;
        lqw[4] = tq4; lqw[5] = tq5; lqw[6] = tq6; lqw[7] = tq7;
    }
    __syncthreads();
    int tt = threadIdx.x;
    if (tt < HID) {
        float ssum = ls[tt] + ls[HID + tt] + ls[2 * HID + tt] + ls[3 * HID + tt];
        float ssq = lq[tt] + lq[HID + tt] + lq[2 * HID + tt] + lq[3 * HID + tt];
        int slot = blockIdx.x & (BSLOT - 1);
        atomicAdd(&psum[slot * HID + tt], ssum);
        atomicAdd(&psq[slot * HID + tt], ssq);
    }
}

// ---------------- segmented pooling, chunked; derives layer-3 BN in-kernel ----------------

__global__ __launch_bounds__(128) void k_pool(const unsigned short* __restrict__ A,
                                              const float* __restrict__ psum,
                                              const float* __restrict__ psq,
                                              const float* __restrict__ gamma,
                                              const float* __restrict__ beta,
                                              const int* __restrict__ gstart,
                                              float* __restrict__ poolPart) {
    int g = blockIdx.x;
    int c = blockIdx.y;
    int f = threadIdx.x;
    float s = 0.f, s2 = 0.f;
#pragma unroll 8
    for (int b = 0; b < BSLOT; b++) {
        s += psum[b * HID + f];
        s2 += psq[b * HID + f];
    }
    const float invN = 1.f / (float)N_NODES;
    float mu = s * invN;
    float var = s2 * invN - mu * mu;
    float sc = rsqrtf(var + EPS) * gamma[f];
    float sh = beta[f] - mu * sc;
    int beg = gstart[g], end = gstart[g + 1];
    int len = end - beg;
    int per = (len + POOL_CHUNKS - 1) / POOL_CHUNKS;
    int s0 = beg + c * per;
    int s1 = min(s0 + per, end);
    float sa = 0.f, sb = 0.f, ma = 0.f, mb = 0.f;
    int n = s0;
    for (; n + 1 < s1; n += 2) {
        float v0 = bf2f(A[(size_t)n * HID + f]);
        float v1 = bf2f(A[(size_t)(n + 1) * HID + f]);
        v0 = fmaxf(v0 * sc + sh, 0.f);
        v1 = fmaxf(v1 * sc + sh, 0.f);
        sa += v0; ma = fmaxf(ma, v0);
        sb += v1; mb = fmaxf(mb, v1);
    }
    if (n < s1) {
        float v = fmaxf(bf2f(A[(size_t)n * HID + f]) * sc + sh, 0.f);
        sa += v; ma = fmaxf(ma, v);
    }
    poolPart[((size_t)g * POOL_CHUNKS + c) * 256 + f] = sa + sb;
    poolPart[((size_t)g * POOL_CHUNKS + c) * 256 + 128 + f] = fmaxf(ma, mb);
}

// ---------------- MLP head ----------------

__global__ __launch_bounds__(128) void k_head(const float* __restrict__ poolPart,
                                              const int* __restrict__ gstart,
                                              const float* __restrict__ W1, const float* __restrict__ b1,
                                              const float* __restrict__ W2, const float* __restrict__ b2,
                                              const float* __restrict__ W3, const float* __restrict__ b3,
                                              float* __restrict__ out) {
    __shared__ float pl[2 * HID];
    __shared__ float h1[HID];
    __shared__ float h2[HID / 2];
    int g = blockIdx.x, t = threadIdx.x;
    float cnt = fmaxf((float)(gstart[g + 1] - gstart[g]), 1.f);
    float s = 0.f, mx = 0.f;
#pragma unroll
    for (int c = 0; c < POOL_CHUNKS; c++) {
        const float* p = &poolPart[((size_t)g * POOL_CHUNKS + c) * 256];
        s += p[t];
        mx = fmaxf(mx, p[128 + t]);
    }
    pl[t] = s / cnt;
    pl[HID + t] = mx;
    __syncthreads();
    float acc = b1[t];
    for (int k = 0; k < 2 * HID; k++) acc += pl[k] * W1[k * HID + t];
    h1[t] = fmaxf(acc, 0.f);
    __syncthreads();
    if (t < HID / 2) {
        float a2 = b2[t];
        for (int k = 0; k < HID; k++) a2 += h1[k] * W2[k * (HID / 2) + t];
        h2[t] = fmaxf(a2, 0.f);
    }
    __syncthreads();
    if (t < NCLS) {
        float a3 = b3[t];
        for (int k = 0; k < HID / 2; k++) a3 += h2[k] * W3[k * NCLS + t];
        out[g * NCLS + t] = a3;
    }
}

extern "C" void kernel_launch(void* const* d_in, const int* in_sizes, int n_in,
                              void* d_out, int out_size, void* d_ws, size_t ws_size,
                              hipStream_t stream) {
    const float* x     = (const float*)d_in[0];
    const int*   ei    = (const int*)d_in[1];
    const int*   batch = (const int*)d_in[2];
    const float* Wp    = (const float*)d_in[3];
    const float* bp    = (const float*)d_in[4];
    const float* Wg    = (const float*)d_in[5];
    const float* bg    = (const float*)d_in[6];
    const float* gamma = (const float*)d_in[7];
    const float* beta  = (const float*)d_in[8];
    const float* W1    = (const float*)d_in[9];
    const float* b1    = (const float*)d_in[10];
    const float* W2    = (const float*)d_in[11];
    const float* b2    = (const float*)d_in[12];
    const float* W3    = (const float*)d_in[13];
    const float* b3    = (const float*)d_in[14];
    const int* src = ei;
    const int* dst = ei + N_EDGES;
    float* out = (float*)d_out;

    char* base = (char*)d_ws;
    size_t off = 0;
    auto alloc = [&](size_t bytes) -> void* {
        void* p = base + off;
        off += (bytes + 255) & ~(size_t)255;
        return p;
    };
    // zeroed region (one memset): bucket cursors + BN slots
    int*   bcur   = (int*)alloc((size_t)NBUCK * 4);
    float* psum   = (float*)alloc((size_t)NLAYERS * BSLOT * HID * 4);
    float* psq    = (float*)alloc((size_t)NLAYERS * BSLOT * HID * 4);
    size_t zeroBytes = off;
    // non-zeroed scratch
    unsigned* ebuf = (unsigned*)alloc((size_t)NBUCK * BCAP * 4);
    int*   bbase   = (int*)alloc((size_t)(NBUCK + 1) * 4);
    int*   rp      = (int*)alloc((size_t)(N_NODES + 1) * 4);
    int*   cwc     = (int*)alloc((size_t)N_EDGES * 4);
    float* dinv    = (float*)alloc((size_t)N_NODES * 4);
    int*   gstart  = (int*)alloc((size_t)(N_GRAPHS + 1) * 4);
    float* poolPart= (float*)alloc((size_t)N_GRAPHS * POOL_CHUNKS * 256 * 4);
    unsigned short* WtG = (unsigned short*)alloc((size_t)NLAYERS * HID * HID * 2);
    unsigned short* A = (unsigned short*)alloc((size_t)N_NODES * HID * 2);
    unsigned short* B = (unsigned short*)alloc((size_t)N_NODES * HID * 2);
    (void)ws_size; (void)in_sizes; (void)n_in; (void)out_size;

    hipMemsetAsync(d_ws, 0, zeroBytes, stream);

    k_bucket<<<EDGE_BLK + 1 + WT_BLK, 256, 0, stream>>>(src, dst, batch, Wg, bcur,
                                                        ebuf, gstart, WtG);
    k_bscan<<<1, 1024, 0, stream>>>(bcur, bbase, rp);
    k_bsort<<<NBUCK, 256, 0, stream>>>(ebuf, bcur, bbase, rp, dinv, cwc);

    for (int i = 0; i < NLAYERS; i++) {
        int pl = (i == 0) ? 0 : (i - 1);
        k_gemmM<<<768, 256, 0, stream>>>(A, x, Wp, bp, WtG + (size_t)i * HID * HID, B,
                                         psum + (size_t)pl * BSLOT * HID,
                                         psq + (size_t)pl * BSLOT * HID,
                                         gamma + pl * HID, beta + pl * HID,
                                         (i == 0) ? 1 : 0);
        k_gather<<<N_NODES / 16, 256, 0, stream>>>((const uint4*)B, rp, cwc, dinv,
                                                   bg + i * HID, A,
                                                   psum + (size_t)i * BSLOT * HID,
                                                   psq + (size_t)i * BSLOT * HID);
    }
    dim3 pg(N_GRAPHS, POOL_CHUNKS);
    k_pool<<<pg, 128, 0, stream>>>(A, psum + (size_t)3 * BSLOT * HID,
                                   psq + (size_t)3 * BSLOT * HID,
                                   gamma + 3 * HID, beta + 3 * HID, gstart, poolPart);
    k_head<<<N_GRAPHS, 128, 0, stream>>>(poolPart, gstart, W1, b1, W2, b2, W3, b3, out);
}

// Round 10
// 374.211 us; speedup vs baseline: 1.2406x; 1.2406x over previous
//
#include <hip/hip_runtime.h>
#include <hip/hip_bf16.h>

#define N_NODES 50000
#define N_EDGES 600000
#define N_GRAPHS 64
#define HID 128
#define NLAYERS 4
#define IN_DIM 5
#define NCLS 5
#define EPS 1e-5f
#define SCAN_BLK ((N_NODES + 511) / 512)
#define FILL_BLK ((N_EDGES + 255) / 256)
#define POOL_CHUNKS 16
#define BSLOT 64  // BN-stat atomic slots (per layer)
#define WS 136    // bf16 LDS row stride (MFMA kernel)

typedef __attribute__((ext_vector_type(8))) short s16x8;
typedef __attribute__((ext_vector_type(4))) float f32x4;

// bf16 helpers (RNE)
__device__ __forceinline__ unsigned short f2bf(float x) {
    unsigned u = __float_as_uint(x);
    unsigned r = (u + 0x7fffu + ((u >> 16) & 1u)) >> 16;
    return (unsigned short)r;
}
__device__ __forceinline__ float2 bfpair(unsigned u) {
    float2 r;
    r.x = __uint_as_float(u << 16);
    r.y = __uint_as_float(u & 0xffff0000u);
    return r;
}
__device__ __forceinline__ float bf2f(unsigned short s) {
    return __uint_as_float(((unsigned)s) << 16);
}

// ---------------- CSR build (separate dispatches: boundaries are ~free, R5) ----------------

__global__ void k_count(const int* __restrict__ dst, int* __restrict__ cnt) {
    int i = blockIdx.x * blockDim.x + threadIdx.x;
    if (i < N_EDGES) atomicAdd(&cnt[dst[i]], 1);
}

__global__ void k_scan1(const int* __restrict__ cnt, int* __restrict__ rp, int* __restrict__ bsum) {
    __shared__ int s[512];
    int t = threadIdx.x;
    int i = blockIdx.x * 512 + t;
    int v = (i < N_NODES) ? cnt[i] : 0;
    s[t] = v;
    __syncthreads();
    for (int off = 1; off < 512; off <<= 1) {
        int x = (t >= off) ? s[t - off] : 0;
        __syncthreads();
        s[t] += x;
        __syncthreads();
    }
    if (i < N_NODES) rp[i + 1] = s[t];
    if (t == 511) bsum[blockIdx.x] = s[511];
}

__global__ void k_scan2g(int* __restrict__ bsum, const int* __restrict__ batch,
                         int* __restrict__ gstart) {
    if (blockIdx.x == 0) {
        __shared__ int s[128];
        int t = threadIdx.x;
        int v = (t < SCAN_BLK) ? bsum[t] : 0;
        s[t] = v;
        __syncthreads();
        for (int off = 1; off < 128; off <<= 1) {
            int x = (t >= off) ? s[t - off] : 0;
            __syncthreads();
            s[t] += x;
            __syncthreads();
        }
        if (t < SCAN_BLK) bsum[t] = s[t] - v;
    } else {
        int t = threadIdx.x;
        if (t <= N_GRAPHS) {
            int lo = 0, hi = N_NODES;
            while (lo < hi) {
                int mid = (lo + hi) >> 1;
                if (batch[mid] < t) lo = mid + 1; else hi = mid;
            }
            gstart[t] = lo;
        }
    }
}

// rp fixup + dinv + cursor primed with the row start (absolute slot base):
// cursor[i] = rp[i] = rp[i+1] - cnt[i]  -> fillw needs only ONE atomic, no rp read.
__global__ void k_scan3d(int* __restrict__ rp, const int* __restrict__ bsum,
                         const int* __restrict__ cnt, float* __restrict__ dinv,
                         int* __restrict__ cursor) {
    int i = blockIdx.x * 512 + threadIdx.x;
    if (i < N_NODES) {
        int c = cnt[i];
        int incl = rp[i + 1] + bsum[blockIdx.x];
        rp[i + 1] = incl;
        cursor[i] = incl - c;  // exclusive start of row i
        dinv[i] = rsqrtf((float)(c + 1));
    }
    if (i == 0) rp[0] = 0;
}

// fill packed col-only entries (w re-derived in gather from L2-resident dinv);
// trailing blocks do the W transpose+bf16 convert.
__global__ void k_fillw(const int* __restrict__ src, const int* __restrict__ dst,
                        int* __restrict__ cursor, int* __restrict__ cwc,
                        const float* __restrict__ Wg, unsigned short* __restrict__ WtG) {
    int b = blockIdx.x;
    if (b < FILL_BLK) {
        int e = b * 256 + threadIdx.x;
        if (e < N_EDGES) {
            int d = dst[e];
            int pos = atomicAdd(&cursor[d], 1);  // absolute slot
            cwc[pos] = src[e];
        }
    } else {
        int idx = (b - FILL_BLK) * 256 + threadIdx.x;  // < NLAYERS*HID*HID
        int l = idx >> 14;
        int r = idx & 16383;
        int n = r >> 7, k = r & 127;
        WtG[idx] = f2bf(Wg[l * HID * HID + k * HID + n]);
    }
}

// ---------------- GEMM (MFMA): Bm(bf16) = act(in) @ W (R2-proven) ----------------

__global__ __launch_bounds__(256, 3) void k_gemmM(const unsigned short* __restrict__ Abf,
                                                  const float* __restrict__ x,
                                                  const float* __restrict__ Wp,
                                                  const float* __restrict__ bp,
                                                  const unsigned short* __restrict__ WtG,
                                                  unsigned short* __restrict__ Bm,
                                                  const float* __restrict__ psum,
                                                  const float* __restrict__ psq,
                                                  const float* __restrict__ gamma,
                                                  const float* __restrict__ beta,
                                                  int layer0) {
    __shared__ unsigned short Wt[HID * WS];
    __shared__ unsigned short Al[64 * WS];
    __shared__ float scl[HID], shf[HID];
    int t = threadIdx.x;
    {
        const uint4* Wg4 = (const uint4*)WtG;
        for (int idx = t; idx < HID * 16; idx += 256) {
            int n = idx >> 4, c = idx & 15;
            *(uint4*)&Wt[n * WS + c * 8] = Wg4[idx];
        }
    }
    if (!layer0 && t < HID) {
        float s = 0.f, s2 = 0.f;
#pragma unroll 8
        for (int b = 0; b < BSLOT; b++) {
            s += psum[b * HID + t];
            s2 += psq[b * HID + t];
        }
        const float invN = 1.f / (float)N_NODES;
        float mu = s * invN;
        float var = s2 * invN - mu * mu;
        float rs = rsqrtf(var + EPS) * gamma[t];
        scl[t] = rs;
        shf[t] = beta[t] - mu * rs;
    }
    int lane = t & 63, wv = t >> 6;
    int rbase = (wv & 1) * 32;
    int cbase = (wv >> 1) * 64;
    int mr = lane & 15, q = lane >> 4;
    const int numTiles = (N_NODES + 63) / 64;
    for (int tile = blockIdx.x; tile < numTiles; tile += gridDim.x) {
        int n0 = tile * 64;
        int limRow = min(64, N_NODES - n0);
        __syncthreads();  // orders scl/Wt writes (1st iter) + Al reuse safety
        if (layer0) {
            for (int idx = t; idx < 64 * HID; idx += 256) {
                int n = idx >> 7, k = idx & 127;
                int node = n0 + n;
                float acc = 0.f;
                if (node < N_NODES) {
                    acc = bp[k];
#pragma unroll
                    for (int j = 0; j < IN_DIM; j++) acc += x[node * IN_DIM + j] * Wp[j * HID + k];
                }
                Al[n * WS + k] = f2bf(acc);
            }
        } else {
            const uint2* Ag = (const uint2*)(Abf + (size_t)n0 * HID);
            for (int idx = t; idx < 64 * 32; idx += 256) {
                int row = idx >> 5, c4 = idx & 31;
                uint2 u = (row < limRow) ? Ag[row * 32 + c4] : make_uint2(0u, 0u);
                float2 ab = bfpair(u.x);
                float2 cd = bfpair(u.y);
                int kf = c4 * 4;
                float4 sc = *(const float4*)&scl[kf];
                float4 sh = *(const float4*)&shf[kf];
                float v0 = fmaxf(ab.x * sc.x + sh.x, 0.f);
                float v1 = fmaxf(ab.y * sc.y + sh.y, 0.f);
                float v2 = fmaxf(cd.x * sc.z + sh.z, 0.f);
                float v3 = fmaxf(cd.y * sc.w + sh.w, 0.f);
                unsigned lo = (unsigned)f2bf(v0) | ((unsigned)f2bf(v1) << 16);
                unsigned hi = (unsigned)f2bf(v2) | ((unsigned)f2bf(v3) << 16);
                *(uint2*)&Al[row * WS + kf] = make_uint2(lo, hi);
            }
        }
        __syncthreads();
        f32x4 acc[2][4];
#pragma unroll
        for (int rt = 0; rt < 2; rt++)
#pragma unroll
            for (int ct = 0; ct < 4; ct++) acc[rt][ct] = (f32x4){0.f, 0.f, 0.f, 0.f};
#pragma unroll
        for (int kk = 0; kk < HID; kk += 32) {
            s16x8 a0 = *(const s16x8*)&Al[(rbase + mr) * WS + kk + q * 8];
            s16x8 a1 = *(const s16x8*)&Al[(rbase + 16 + mr) * WS + kk + q * 8];
#pragma unroll
            for (int ct = 0; ct < 4; ct++) {
                s16x8 b = *(const s16x8*)&Wt[(cbase + ct * 16 + mr) * WS + kk + q * 8];
                acc[0][ct] = __builtin_amdgcn_mfma_f32_16x16x32_bf16(a0, b, acc[0][ct], 0, 0, 0);
                acc[1][ct] = __builtin_amdgcn_mfma_f32_16x16x32_bf16(a1, b, acc[1][ct], 0, 0, 0);
            }
        }
        __syncthreads();  // all waves done reading Al fragments
        // stage C tile into Al (bf16), then coalesced uint4 global stores
#pragma unroll
        for (int rt = 0; rt < 2; rt++)
#pragma unroll
            for (int ct = 0; ct < 4; ct++)
#pragma unroll
                for (int r = 0; r < 4; r++) {
                    int rloc = rbase + rt * 16 + q * 4 + r;
                    int f = cbase + ct * 16 + mr;
                    Al[rloc * WS + f] = f2bf(acc[rt][ct][r]);
                }
        __syncthreads();
        for (int idx = t; idx < 64 * 16; idx += 256) {
            int row = idx >> 4, c = idx & 15;
            if (row < limRow)
                *(uint4*)&Bm[(size_t)(n0 + row) * HID + c * 8] = *(const uint4*)&Al[row * WS + c * 8];
        }
    }
}

// ---------------- CSR gather + fused BN partial stats (R8-proven) ----------------
// cw is col-only; w = dinv[col] fetched per edge (dinv = 200KB, L2-resident in
// every XCD; broadcast load, issued independent of the row-data load).

__global__ __launch_bounds__(256) void k_gather(const uint4* __restrict__ Bm4,
                                                const int* __restrict__ rp,
                                                const int* __restrict__ cwc,
                                                const float* __restrict__ dinv,
                                                const float* __restrict__ bg,
                                                unsigned short* __restrict__ Aout,
                                                float* __restrict__ psum,
                                                float* __restrict__ psq) {
    __shared__ float ls[4 * HID], lq[4 * HID];
    int wave = threadIdx.x >> 6;
    int lane = threadIdx.x & 63;
    int s = lane & 15;   // 16B feature chunk: features s*8 .. s*8+7
    int p = lane >> 4;   // node slot 0..3 within wave
    int f = s * 8;
    int v = blockIdx.x * 16 + wave * 4 + p;
    int beg = rp[v], end = rp[v + 1];
    float dv = dinv[v];
    float a0, a1, a2, a3, a4, a5, a6, a7;
    {
        uint4 u = Bm4[(size_t)v * 16 + s];
        float2 q0 = bfpair(u.x), q1 = bfpair(u.y), q2 = bfpair(u.z), q3 = bfpair(u.w);
        a0 = q0.x * dv; a1 = q0.y * dv; a2 = q1.x * dv; a3 = q1.y * dv;
        a4 = q2.x * dv; a5 = q2.y * dv; a6 = q3.x * dv; a7 = q3.y * dv;
    }
    int e = beg;
    for (; e + 1 < end; e += 2) {
        int c0 = cwc[e];
        int c1 = cwc[e + 1];
        uint4 u0 = Bm4[(size_t)c0 * 16 + s];
        uint4 u1 = Bm4[(size_t)c1 * 16 + s];
        float w0 = dinv[c0];
        float w1 = dinv[c1];
        float2 x0 = bfpair(u0.x), x1 = bfpair(u0.y), x2 = bfpair(u0.z), x3 = bfpair(u0.w);
        float2 y0 = bfpair(u1.x), y1 = bfpair(u1.y), y2 = bfpair(u1.z), y3 = bfpair(u1.w);
        a0 += x0.x * w0 + y0.x * w1;
        a1 += x0.y * w0 + y0.y * w1;
        a2 += x1.x * w0 + y1.x * w1;
        a3 += x1.y * w0 + y1.y * w1;
        a4 += x2.x * w0 + y2.x * w1;
        a5 += x2.y * w0 + y2.y * w1;
        a6 += x3.x * w0 + y3.x * w1;
        a7 += x3.y * w0 + y3.y * w1;
    }
    if (e < end) {
        int c0 = cwc[e];
        uint4 u = Bm4[(size_t)c0 * 16 + s];
        float w = dinv[c0];
        float2 x0 = bfpair(u.x), x1 = bfpair(u.y), x2 = bfpair(u.z), x3 = bfpair(u.w);
        a0 += x0.x * w; a1 += x0.y * w; a2 += x1.x * w; a3 += x1.y * w;
        a4 += x2.x * w; a5 += x2.y * w; a6 += x3.x * w; a7 += x3.y * w;
    }
    float r0 = a0 * dv + bg[f + 0];
    float r1 = a1 * dv + bg[f + 1];
    float r2 = a2 * dv + bg[f + 2];
    float r3 = a3 * dv + bg[f + 3];
    float r4 = a4 * dv + bg[f + 4];
    float r5 = a5 * dv + bg[f + 5];
    float r6 = a6 * dv + bg[f + 6];
    float r7 = a7 * dv + bg[f + 7];
    unsigned short b0 = f2bf(r0), b1 = f2bf(r1), b2 = f2bf(r2), b3 = f2bf(r3);
    unsigned short b4 = f2bf(r4), b5 = f2bf(r5), b6 = f2bf(r6), b7 = f2bf(r7);
    uint4 o;
    o.x = (unsigned)b0 | ((unsigned)b1 << 16);
    o.y = (unsigned)b2 | ((unsigned)b3 << 16);
    o.z = (unsigned)b4 | ((unsigned)b5 << 16);
    o.w = (unsigned)b6 | ((unsigned)b7 << 16);
    *(uint4*)&Aout[(size_t)v * HID + f] = o;
    // BN stats on the bf16-rounded values (what the next GEMM sees)
    float v0 = bf2f(b0), v1 = bf2f(b1), v2 = bf2f(b2), v3 = bf2f(b3);
    float v4 = bf2f(b4), v5 = bf2f(b5), v6 = bf2f(b6), v7 = bf2f(b7);
    float ts0 = v0, ts1 = v1, ts2 = v2, ts3 = v3;
    float ts4 = v4, ts5 = v5, ts6 = v6, ts7 = v7;
    float tq0 = v0 * v0, tq1 = v1 * v1, tq2 = v2 * v2, tq3 = v3 * v3;
    float tq4 = v4 * v4, tq5 = v5 * v5, tq6 = v6 * v6, tq7 = v7 * v7;
    ts0 += __shfl_xor(ts0, 16); ts1 += __shfl_xor(ts1, 16);
    ts2 += __shfl_xor(ts2, 16); ts3 += __shfl_xor(ts3, 16);
    ts4 += __shfl_xor(ts4, 16); ts5 += __shfl_xor(ts5, 16);
    ts6 += __shfl_xor(ts6, 16); ts7 += __shfl_xor(ts7, 16);
    tq0 += __shfl_xor(tq0, 16); tq1 += __shfl_xor(tq1, 16);
    tq2 += __shfl_xor(tq2, 16); tq3 += __shfl_xor(tq3, 16);
    tq4 += __shfl_xor(tq4, 16); tq5 += __shfl_xor(tq5, 16);
    tq6 += __shfl_xor(tq6, 16); tq7 += __shfl_xor(tq7, 16);
    ts0 += __shfl_xor(ts0, 32); ts1 += __shfl_xor(ts1, 32);
    ts2 += __shfl_xor(ts2, 32); ts3 += __shfl_xor(ts3, 32);
    ts4 += __shfl_xor(ts4, 32); ts5 += __shfl_xor(ts5, 32);
    ts6 += __shfl_xor(ts6, 32); ts7 += __shfl_xor(ts7, 32);
    tq0 += __shfl_xor(tq0, 32); tq1 += __shfl_xor(tq1, 32);
    tq2 += __shfl_xor(tq2, 32); tq3 += __shfl_xor(tq3, 32);
    tq4 += __shfl_xor(tq4, 32); tq5 += __shfl_xor(tq5, 32);
    tq6 += __shfl_xor(tq6, 32); tq7 += __shfl_xor(tq7, 32);
    if (p == 0) {
        float* lsw = &ls[wave * HID + f];
        float* lqw = &lq[wave * HID + f];
        lsw[0] = ts0; lsw[1] = ts1; lsw[2] = ts2; lsw[3] = ts3;
        lsw[4] = ts4; lsw[5] = ts5; lsw[6] = ts6; lsw[7] = ts7;
        lqw[0] = tq0; lqw[1] = tq1; lqw[2] = tq2; lqw[3] = tq3;
        lqw[4] = tq4; lqw[5] = tq5; lqw[6] = tq6; lqw[7] = tq7;
    }
    __syncthreads();
    int tt = threadIdx.x;
    if (tt < HID) {
        float ssum = ls[tt] + ls[HID + tt] + ls[2 * HID + tt] + ls[3 * HID + tt];
        float ssq = lq[tt] + lq[HID + tt] + lq[2 * HID + tt] + lq[3 * HID + tt];
        int slot = blockIdx.x & (BSLOT - 1);
        atomicAdd(&psum[slot * HID + tt], ssum);
        atomicAdd(&psq[slot * HID + tt], ssq);
    }
}

// ---------------- segmented pooling, chunked; derives layer-3 BN in-kernel ----------------

__global__ __launch_bounds__(128) void k_pool(const unsigned short* __restrict__ A,
                                              const float* __restrict__ psum,
                                              const float* __restrict__ psq,
                                              const float* __restrict__ gamma,
                                              const float* __restrict__ beta,
                                              const int* __restrict__ gstart,
                                              float* __restrict__ poolPart) {
    int g = blockIdx.x;
    int c = blockIdx.y;
    int f = threadIdx.x;
    float s = 0.f, s2 = 0.f;
#pragma unroll 8
    for (int b = 0; b < BSLOT; b++) {
        s += psum[b * HID + f];
        s2 += psq[b * HID + f];
    }
    const float invN = 1.f / (float)N_NODES;
    float mu = s * invN;
    float var = s2 * invN - mu * mu;
    float sc = rsqrtf(var + EPS) * gamma[f];
    float sh = beta[f] - mu * sc;
    int beg = gstart[g], end = gstart[g + 1];
    int len = end - beg;
    int per = (len + POOL_CHUNKS - 1) / POOL_CHUNKS;
    int s0 = beg + c * per;
    int s1 = min(s0 + per, end);
    float sa = 0.f, sb = 0.f, ma = 0.f, mb = 0.f;
    int n = s0;
    for (; n + 1 < s1; n += 2) {
        float v0 = bf2f(A[(size_t)n * HID + f]);
        float v1 = bf2f(A[(size_t)(n + 1) * HID + f]);
        v0 = fmaxf(v0 * sc + sh, 0.f);
        v1 = fmaxf(v1 * sc + sh, 0.f);
        sa += v0; ma = fmaxf(ma, v0);
        sb += v1; mb = fmaxf(mb, v1);
    }
    if (n < s1) {
        float v = fmaxf(bf2f(A[(size_t)n * HID + f]) * sc + sh, 0.f);
        sa += v; ma = fmaxf(ma, v);
    }
    poolPart[((size_t)g * POOL_CHUNKS + c) * 256 + f] = sa + sb;
    poolPart[((size_t)g * POOL_CHUNKS + c) * 256 + 128 + f] = fmaxf(ma, mb);
}

// ---------------- MLP head ----------------

__global__ __launch_bounds__(128) void k_head(const float* __restrict__ poolPart,
                                              const int* __restrict__ gstart,
                                              const float* __restrict__ W1, const float* __restrict__ b1,
                                              const float* __restrict__ W2, const float* __restrict__ b2,
                                              const float* __restrict__ W3, const float* __restrict__ b3,
                                              float* __restrict__ out) {
    __shared__ float pl[2 * HID];
    __shared__ float h1[HID];
    __shared__ float h2[HID / 2];
    int g = blockIdx.x, t = threadIdx.x;
    float cnt = fmaxf((float)(gstart[g + 1] - gstart[g]), 1.f);
    float s = 0.f, mx = 0.f;
#pragma unroll
    for (int c = 0; c < POOL_CHUNKS; c++) {
        const float* p = &poolPart[((size_t)g * POOL_CHUNKS + c) * 256];
        s += p[t];
        mx = fmaxf(mx, p[128 + t]);
    }
    pl[t] = s / cnt;
    pl[HID + t] = mx;
    __syncthreads();
    float acc = b1[t];
    for (int k = 0; k < 2 * HID; k++) acc += pl[k] * W1[k * HID + t];
    h1[t] = fmaxf(acc, 0.f);
    __syncthreads();
    if (t < HID / 2) {
        float a2 = b2[t];
        for (int k = 0; k < HID; k++) a2 += h1[k] * W2[k * (HID / 2) + t];
        h2[t] = fmaxf(a2, 0.f);
    }
    __syncthreads();
    if (t < NCLS) {
        float a3 = b3[t];
        for (int k = 0; k < HID / 2; k++) a3 += h2[k] * W3[k * NCLS + t];
        out[g * NCLS + t] = a3;
    }
}

extern "C" void kernel_launch(void* const* d_in, const int* in_sizes, int n_in,
                              void* d_out, int out_size, void* d_ws, size_t ws_size,
                              hipStream_t stream) {
    const float* x     = (const float*)d_in[0];
    const int*   ei    = (const int*)d_in[1];
    const int*   batch = (const int*)d_in[2];
    const float* Wp    = (const float*)d_in[3];
    const float* bp    = (const float*)d_in[4];
    const float* Wg    = (const float*)d_in[5];
    const float* bg    = (const float*)d_in[6];
    const float* gamma = (const float*)d_in[7];
    const float* beta  = (const float*)d_in[8];
    const float* W1    = (const float*)d_in[9];
    const float* b1    = (const float*)d_in[10];
    const float* W2    = (const float*)d_in[11];
    const float* b2    = (const float*)d_in[12];
    const float* W3    = (const float*)d_in[13];
    const float* b3    = (const float*)d_in[14];
    const int* src = ei;
    const int* dst = ei + N_EDGES;
    float* out = (float*)d_out;

    char* base = (char*)d_ws;
    size_t off = 0;
    auto alloc = [&](size_t bytes) -> void* {
        void* p = base + off;
        off += (bytes + 255) & ~(size_t)255;
        return p;
    };
    // zeroed region (one memset); cursor no longer needs zeroing (primed in scan3d)
    int*   counts = (int*)alloc((size_t)N_NODES * 4);
    float* psum   = (float*)alloc((size_t)NLAYERS * BSLOT * HID * 4);
    float* psq    = (float*)alloc((size_t)NLAYERS * BSLOT * HID * 4);
    size_t zeroBytes = off;
    // non-zeroed scratch
    int*   cursor  = (int*)alloc((size_t)N_NODES * 4);
    int*   rp      = (int*)alloc((size_t)(N_NODES + 1) * 4);
    int*   bsum    = (int*)alloc(128 * 4);
    int*   cwc     = (int*)alloc((size_t)N_EDGES * 4);
    float* dinv    = (float*)alloc((size_t)N_NODES * 4);
    int*   gstart  = (int*)alloc((size_t)(N_GRAPHS + 1) * 4);
    float* poolPart= (float*)alloc((size_t)N_GRAPHS * POOL_CHUNKS * 256 * 4);
    unsigned short* WtG = (unsigned short*)alloc((size_t)NLAYERS * HID * HID * 2);
    unsigned short* A = (unsigned short*)alloc((size_t)N_NODES * HID * 2);
    unsigned short* B = (unsigned short*)alloc((size_t)N_NODES * HID * 2);
    (void)ws_size; (void)in_sizes; (void)n_in; (void)out_size;

    hipMemsetAsync(d_ws, 0, zeroBytes, stream);

    k_count<<<(N_EDGES + 255) / 256, 256, 0, stream>>>(dst, counts);
    k_scan1<<<SCAN_BLK, 512, 0, stream>>>(counts, rp, bsum);
    k_scan2g<<<2, 128, 0, stream>>>(bsum, batch, gstart);
    k_scan3d<<<SCAN_BLK, 512, 0, stream>>>(rp, bsum, counts, dinv, cursor);
    k_fillw<<<(N_EDGES + 255) / 256 + (NLAYERS * HID * HID) / 256, 256, 0, stream>>>(
        src, dst, cursor, cwc, Wg, WtG);

    for (int i = 0; i < NLAYERS; i++) {
        int pl = (i == 0) ? 0 : (i - 1);
        k_gemmM<<<768, 256, 0, stream>>>(A, x, Wp, bp, WtG + (size_t)i * HID * HID, B,
                                         psum + (size_t)pl * BSLOT * HID,
                                         psq + (size_t)pl * BSLOT * HID,
                                         gamma + pl * HID, beta + pl * HID,
                                         (i == 0) ? 1 : 0);
        k_gather<<<N_NODES / 16, 256, 0, stream>>>((const uint4*)B, rp, cwc, dinv,
                                                   bg + i * HID, A,
                                                   psum + (size_t)i * BSLOT * HID,
                                                   psq + (size_t)i * BSLOT * HID);
    }
    dim3 pg(N_GRAPHS, POOL_CHUNKS);
    k_pool<<<pg, 128, 0, stream>>>(A, psum + (size_t)3 * BSLOT * HID,
                                   psq + (size_t)3 * BSLOT * HID,
                                   gamma + 3 * HID, beta + 3 * HID, gstart, poolPart);
    k_head<<<N_GRAPHS, 128, 0, stream>>>(poolPart, gstart, W1, b1, W2, b2, W3, b3, out);
}